// Round 17
// baseline (163.928 us; speedup 1.0000x reference)
//
#include <hip/hip_runtime.h>

#define N_NODES 100000
#define N_EDGES 1600000
#define DIM 128

#define BSHIFT 8
#define BNODES 256
#define NBUCK 391     // ceil(100000/256)
#define BCAP  4608    // padded bucket capacity
#define PCHUNK 2048   // smaller chunks -> 782 part blocks (~3/CU, latency-bound phase)
#define NB_PART ((N_EDGES + PCHUNK - 1) / PCHUNK)  // 782

#define GTILES 1563   // ceil(100000/64); one tile per block

#define HALF_ELEMS ((size_t)N_NODES * 64)   // one 64-col half-plane of h1

typedef short s16x8 __attribute__((ext_vector_type(8)));
typedef float f32x4 __attribute__((ext_vector_type(4)));

__device__ __forceinline__ unsigned short f2bf(float f) {
    unsigned u = __float_as_uint(f);
    u += 0x7fffu + ((u >> 16) & 1u);   // RNE
    return (unsigned short)(u >> 16);
}
__device__ __forceinline__ float bflo(unsigned u) { return __uint_as_float(u << 16); }
__device__ __forceinline__ float bfhi(unsigned u) { return __uint_as_float(u & 0xffff0000u); }

__device__ __forceinline__ void acc8(float (&a)[8], uint4 v, float w) {
    a[0] = fmaf(bflo(v.x), w, a[0]); a[1] = fmaf(bfhi(v.x), w, a[1]);
    a[2] = fmaf(bflo(v.y), w, a[2]); a[3] = fmaf(bfhi(v.y), w, a[3]);
    a[4] = fmaf(bflo(v.z), w, a[4]); a[5] = fmaf(bfhi(v.z), w, a[5]);
    a[6] = fmaf(bflo(v.w), w, a[6]); a[7] = fmaf(bfhi(v.w), w, a[7]);
}

// ---------------- CSR build (padded buckets, packed 4B ebuf entries) ----------------
// entry = (src << 8) | (dst & 255); bucket = dst >> 8 (implicit in position)

__global__ void k_zero(int* __restrict__ gcur) {
    int t = blockIdx.x * blockDim.x + threadIdx.x;
    if (t < NBUCK) gcur[t] = t * BCAP;
}

// standalone partition: tiny LDS (~3.2KB) -> high occupancy for the scatter
__global__ __launch_bounds__(256) void k_part(const int* __restrict__ src,
                                              const int* __restrict__ dst,
                                              int* __restrict__ gcur,
                                              int* __restrict__ ebuf) {
    __shared__ int hist[NBUCK];
    __shared__ int gbase[NBUCK];
    int tid = threadIdx.x;
    long e0 = (long)blockIdx.x * PCHUNK;
    int n = min(PCHUNK, (int)(N_EDGES - e0));
    for (int b = tid; b < NBUCK; b += 256) hist[b] = 0;
    __syncthreads();

    int pk[PCHUNK / 256], mybk[PCHUNK / 256];
#pragma unroll
    for (int k = 0; k < PCHUNK / 256; ++k) {
        int idx = k * 256 + tid;
        if (idx < n) {
            int s = src[e0 + idx], d = dst[e0 + idx];
            mybk[k] = d >> BSHIFT;
            pk[k] = (s << 8) | (d & 255);
            atomicAdd(&hist[mybk[k]], 1);
        } else {
            mybk[k] = -1;
        }
    }
    __syncthreads();
    for (int b = tid; b < NBUCK; b += 256) {
        gbase[b] = hist[b] ? atomicAdd(&gcur[b], hist[b]) : 0;
        hist[b] = 0;
    }
    __syncthreads();
#pragma unroll
    for (int k = 0; k < PCHUNK / 256; ++k) {
        if (mybk[k] >= 0) {
            int b = mybk[k];
            int slot = gbase[b] + atomicAdd(&hist[b], 1);
            ebuf[slot] = pk[k];
        }
    }
}

// merged CSR: count, scan, emit src-only lists (one bucket per block; ~2KB LDS)
__global__ __launch_bounds__(256) void k_csrk(const int* __restrict__ ebuf,
                                              const int* __restrict__ gcur,
                                              int* __restrict__ rp,
                                              int* __restrict__ cnt,
                                              float* __restrict__ dinv,
                                              int* __restrict__ csrs) {
    __shared__ int lcnt[BNODES];
    __shared__ int lcur[BNODES];
    int b = blockIdx.x, t = threadIdx.x;
    int node0 = b << BSHIFT;
    lcnt[t] = 0;
    __syncthreads();
    int base = b * BCAP, end = gcur[b];
    for (int e = base + t; e < end; e += 256)
        atomicAdd(&lcnt[ebuf[e] & 255], 1);
    __syncthreads();
    int c = lcnt[t];
    lcur[t] = c;
    __syncthreads();
    for (int s = 1; s < 256; s <<= 1) {
        int u = (t >= s) ? lcur[t - s] : 0;
        __syncthreads();
        lcur[t] += u;
        __syncthreads();
    }
    int excl = lcur[t] - c;
    lcur[t] = excl;           // becomes emit cursor
    int node = node0 + t;
    if (node < N_NODES) {
        rp[node] = base + excl;
        cnt[node] = c;
        dinv[node] = rsqrtf((float)(c + 1));
    }
    __syncthreads();
    for (int e = base + t; e < end; e += 256) {
        int pkd = ebuf[e];
        int p = atomicAdd(&lcur[pkd & 255], 1);
        csrs[base + p] = (int)((unsigned)pkd >> 8);
    }
}

// ---- GEMM: h1h(bf16, [2][N][64] half-planes) = x @ W1, one 64-row tile/block ----
__global__ __launch_bounds__(256) void k_gemm(const float* __restrict__ x,
                                              const float* __restrict__ W1,
                                              unsigned short* __restrict__ h1h) {
    __shared__ __align__(16) char smem[49152];
    int tile = blockIdx.x;
    unsigned short* Wt = (unsigned short*)smem;           // 32 KB
    int tid = threadIdx.x;
    for (int idx = tid; idx < DIM * DIM; idx += 256) {
        int k = idx >> 7, c = idx & 127;
        Wt[c * 128 + (k ^ ((c & 7) << 3))] = f2bf(W1[idx]);
    }
    __syncthreads();

    int wv = tid >> 6, lane = tid & 63;
    int g = lane >> 4, tl = lane & 15;
    unsigned short* cst = (unsigned short*)(smem + 32768 + wv * 4096);

    int rb = tile * 64 + wv * 16;
    if (rb >= N_NODES) return;

    s16x8 afrag[4];
    const float* xrow = x + (size_t)(rb + tl) * DIM + g * 8;
#pragma unroll
    for (int kc = 0; kc < 4; ++kc) {
        float4 p0 = *(const float4*)(xrow + kc * 32);
        float4 p1 = *(const float4*)(xrow + kc * 32 + 4);
        s16x8 a;
        a[0] = (short)f2bf(p0.x); a[1] = (short)f2bf(p0.y);
        a[2] = (short)f2bf(p0.z); a[3] = (short)f2bf(p0.w);
        a[4] = (short)f2bf(p1.x); a[5] = (short)f2bf(p1.y);
        a[6] = (short)f2bf(p1.z); a[7] = (short)f2bf(p1.w);
        afrag[kc] = a;
    }

    f32x4 acc[8];
#pragma unroll
    for (int ct = 0; ct < 8; ++ct) acc[ct] = (f32x4)0.0f;
#pragma unroll
    for (int kc = 0; kc < 4; ++kc) {
#pragma unroll
        for (int ct = 0; ct < 8; ++ct) {
            int crow = ct * 16 + tl;
            int boff = crow * 256 + ((kc * 64 + g * 16) ^ ((crow & 7) << 4));
            s16x8 b = *(const s16x8*)((const char*)Wt + boff);
            acc[ct] = __builtin_amdgcn_mfma_f32_16x16x32_bf16(afrag[kc], b, acc[ct], 0, 0, 0);
        }
    }

#pragma unroll
    for (int ct = 0; ct < 8; ++ct) {
#pragma unroll
        for (int r = 0; r < 4; ++r) {
            float own = acc[ct][r];
            float oth = __shfl_xor(own, 1, 64);
            if ((lane & 1) == 0) {
                unsigned pk = (unsigned)f2bf(own) | ((unsigned)f2bf(oth) << 16);
                int row = g * 4 + r;
                int col = ct * 16 + tl;
                *(unsigned*)&cst[row * 128 + (col ^ (row << 3))] = pk;
            }
        }
    }
    asm volatile("s_waitcnt lgkmcnt(0)" ::: "memory");

    int hf = tl >> 3, ch = (tl & 7) * 8;   // half-plane / col-within-half
#pragma unroll
    for (int c = 0; c < 4; ++c) {
        int row = c * 4 + g;
        uint4 v = *(const uint4*)&cst[row * 128 + ((tl ^ row) * 8)];
        *(uint4*)(h1h + (size_t)hf * HALF_ELEMS + (size_t)(rb + row) * 64 + ch) = v;
    }
}

// ---------------- agg1 halved (R13 winner): half = blockIdx&1 ----------------

__global__ __launch_bounds__(256) void k_agg1h(const unsigned short* __restrict__ h1h,
                                               const float* __restrict__ dinv,
                                               const int* __restrict__ rp,
                                               const int* __restrict__ cnt,
                                               const int* __restrict__ csrs,
                                               const float* __restrict__ b1,
                                               const float* __restrict__ W2,
                                               float* __restrict__ zpart) {
    int half = blockIdx.x & 1;
    int nb = blockIdx.x >> 1;            // 0..3124
    int lane = threadIdx.x & 63;
    int wv = threadIdx.x >> 6;
    int g = lane >> 3, tl = lane & 7;
    int i = nb * 32 + wv * 8 + g;
    int c0 = tl * 8;                     // col within half
    const unsigned short* hbase = h1h + (size_t)half * HALF_ELEMS + c0;
    float di = dinv[i];
    int beg = rp[i], end = beg + cnt[i];
    float a[8];
#pragma unroll
    for (int q = 0; q < 8; ++q) a[q] = 0.f;

    int j = beg;
    for (; j + 4 <= end; j += 4) {
        int s0 = csrs[j], s1 = csrs[j + 1], s2 = csrs[j + 2], s3 = csrs[j + 3];
        uint4 v0 = *(const uint4*)(hbase + (size_t)s0 * 64);
        uint4 v1 = *(const uint4*)(hbase + (size_t)s1 * 64);
        uint4 v2 = *(const uint4*)(hbase + (size_t)s2 * 64);
        uint4 v3 = *(const uint4*)(hbase + (size_t)s3 * 64);
        float w0 = dinv[s0] * di, w1 = dinv[s1] * di;
        float w2 = dinv[s2] * di, w3 = dinv[s3] * di;
        acc8(a, v0, w0);
        acc8(a, v1, w1);
        acc8(a, v2, w2);
        acc8(a, v3, w3);
    }
    for (; j < end; ++j) {
        int s0 = csrs[j];
        uint4 v0 = *(const uint4*)(hbase + (size_t)s0 * 64);
        acc8(a, v0, dinv[s0] * di);
    }

    uint4 vs = *(const uint4*)(hbase + (size_t)i * 64);
    float sii = di * di;
    int cb = half * 64 + c0;
    float4 bA = *(const float4*)(b1 + cb);
    float4 bB = *(const float4*)(b1 + cb + 4);
    float4 wA = *(const float4*)(W2 + cb);
    float4 wB = *(const float4*)(W2 + cb + 4);
    float p = 0.f;
    p += fmaxf(fmaf(bflo(vs.x), sii, a[0]) + bA.x, 0.f) * wA.x;
    p += fmaxf(fmaf(bfhi(vs.x), sii, a[1]) + bA.y, 0.f) * wA.y;
    p += fmaxf(fmaf(bflo(vs.y), sii, a[2]) + bA.z, 0.f) * wA.z;
    p += fmaxf(fmaf(bfhi(vs.y), sii, a[3]) + bA.w, 0.f) * wA.w;
    p += fmaxf(fmaf(bflo(vs.z), sii, a[4]) + bB.x, 0.f) * wB.x;
    p += fmaxf(fmaf(bfhi(vs.z), sii, a[5]) + bB.y, 0.f) * wB.y;
    p += fmaxf(fmaf(bflo(vs.w), sii, a[6]) + bB.z, 0.f) * wB.z;
    p += fmaxf(fmaf(bfhi(vs.w), sii, a[7]) + bB.w, 0.f) * wB.w;
#pragma unroll
    for (int off = 4; off >= 1; off >>= 1) p += __shfl_xor(p, off, 64);
    if (tl == 0) zpart[(size_t)half * N_NODES + i] = p;
}

// ---------------- agg2: 4 lanes/node, zred folded in (z = zp0 + zp1) ----------------

__global__ __launch_bounds__(256) void k_agg2(const float* __restrict__ zpart,
                                              const float* __restrict__ dinv,
                                              const int* __restrict__ rp,
                                              const int* __restrict__ cnt,
                                              const int* __restrict__ csrs,
                                              const float* __restrict__ b2,
                                              float* __restrict__ out) {
    int grp = threadIdx.x >> 2, r = threadIdx.x & 3;
    int i = blockIdx.x * 64 + grp;
    if (i >= N_NODES) return;
    float di = dinv[i];
    int beg = rp[i], end = beg + cnt[i];
    float acc = 0.f;
    for (int j = beg + r; j < end; j += 4) {
        int s = csrs[j];
        float zs = zpart[s] + zpart[N_NODES + s];
        acc = fmaf(zs, dinv[s] * di, acc);
    }
    acc += __shfl_xor(acc, 1, 64);
    acc += __shfl_xor(acc, 2, 64);
    if (r == 0) {
        float zi = zpart[i] + zpart[N_NODES + i];
        out[i] = acc + zi * di * di + b2[0];
    }
}

// ---------------- launch ----------------

extern "C" void kernel_launch(void* const* d_in, const int* in_sizes, int n_in,
                              void* d_out, int out_size, void* d_ws, size_t ws_size,
                              hipStream_t stream) {
    const float* x  = (const float*)d_in[0];
    const int*   ei = (const int*)d_in[1];
    const float* W1 = (const float*)d_in[2];
    const float* b1 = (const float*)d_in[3];
    const float* W2 = (const float*)d_in[4];
    const float* b2 = (const float*)d_in[5];
    float* out = (float*)d_out;

    const int* src = ei;
    const int* dst = ei + N_EDGES;

    char* ws = (char*)d_ws;
    size_t o = 0;
    auto take = [&](size_t bytes) { char* p = ws + o; o += (bytes + 255) & ~(size_t)255; return p; };
    int*   cnt   = (int*)take(sizeof(int) * N_NODES);
    int*   rp    = (int*)take(sizeof(int) * N_NODES);
    int*   gcur  = (int*)take(sizeof(int) * (NBUCK + 1));
    float* dinv  = (float*)take(sizeof(float) * N_NODES);
    float* zpart = (float*)take(sizeof(float) * 2 * N_NODES);
    int*   csrs  = (int*)take(sizeof(int) * (size_t)NBUCK * BCAP);
    unsigned short* h1h = (unsigned short*)take(sizeof(unsigned short) * 2 * HALF_ELEMS);
    int* ebuf_sep = (int*)take(sizeof(int) * (size_t)NBUCK * BCAP);
    bool sep = (o <= ws_size);
    int* ebuf = sep ? ebuf_sep : (int*)h1h;  // fallback alias: ebuf dead before gemm writes h1h

    k_zero<<<2, 256, 0, stream>>>(gcur);
    k_part<<<NB_PART, 256, 0, stream>>>(src, dst, gcur, ebuf);
    k_csrk<<<NBUCK, 256, 0, stream>>>(ebuf, gcur, rp, cnt, dinv, csrs);
    k_gemm<<<GTILES, 256, 0, stream>>>(x, W1, h1h);  // after last ebuf read
    k_agg1h<<<2 * (N_NODES / 32), 256, 0, stream>>>(h1h, dinv, rp, cnt, csrs, b1, W2, zpart);
    k_agg2<<<(N_NODES + 63) / 64, 256, 0, stream>>>(zpart, dinv, rp, cnt, csrs, b2, out);
}

// Round 18
// 144.170 us; speedup vs baseline: 1.1370x; 1.1370x over previous
//
#include <hip/hip_runtime.h>

#define N_NODES 100000
#define N_EDGES 1600000
#define DIM 128

#define BSHIFT 8
#define BNODES 256
#define NBUCK 391     // ceil(100000/256)
#define BCAP  4608    // padded bucket capacity
#define PCHUNK 4096
#define NB_PART ((N_EDGES + PCHUNK - 1) / PCHUNK)  // 391

#define GTILES 1563   // ceil(100000/64); one tile per block (R12-best interleave)

#define HALF_ELEMS ((size_t)N_NODES * 64)   // one 64-col half-plane of h1

typedef short s16x8 __attribute__((ext_vector_type(8)));
typedef float f32x4 __attribute__((ext_vector_type(4)));

__device__ __forceinline__ unsigned short f2bf(float f) {
    unsigned u = __float_as_uint(f);
    u += 0x7fffu + ((u >> 16) & 1u);   // RNE
    return (unsigned short)(u >> 16);
}
__device__ __forceinline__ float bflo(unsigned u) { return __uint_as_float(u << 16); }
__device__ __forceinline__ float bfhi(unsigned u) { return __uint_as_float(u & 0xffff0000u); }

__device__ __forceinline__ void acc8(float (&a)[8], uint4 v, float w) {
    a[0] = fmaf(bflo(v.x), w, a[0]); a[1] = fmaf(bfhi(v.x), w, a[1]);
    a[2] = fmaf(bflo(v.y), w, a[2]); a[3] = fmaf(bfhi(v.y), w, a[3]);
    a[4] = fmaf(bflo(v.z), w, a[4]); a[5] = fmaf(bfhi(v.z), w, a[5]);
    a[6] = fmaf(bflo(v.w), w, a[6]); a[7] = fmaf(bfhi(v.w), w, a[7]);
}

// ---------------- CSR build (padded buckets, packed 4B ebuf entries) ----------------
// entry = (src << 8) | (dst & 255); bucket = dst >> 8 (implicit in position)

__global__ void k_zero(int* __restrict__ gcur) {
    int t = blockIdx.x * blockDim.x + threadIdx.x;
    if (t < NBUCK) gcur[t] = t * BCAP;
}

__device__ __forceinline__ void part_body(char* smem, int bid,
                                          const int* __restrict__ src,
                                          const int* __restrict__ dst,
                                          int* __restrict__ gcur,
                                          int* __restrict__ ebuf) {
    int* hist = (int*)smem;
    int* gbase = hist + NBUCK;
    int tid = threadIdx.x;
    long e0 = (long)bid * PCHUNK;
    int n = min(PCHUNK, (int)(N_EDGES - e0));
    for (int b = tid; b < NBUCK; b += 256) hist[b] = 0;
    __syncthreads();

    int pk[16], mybk[16];
#pragma unroll
    for (int k = 0; k < 16; ++k) {
        int idx = k * 256 + tid;
        if (idx < n) {
            int s = src[e0 + idx], d = dst[e0 + idx];
            mybk[k] = d >> BSHIFT;
            pk[k] = (s << 8) | (d & 255);
            atomicAdd(&hist[mybk[k]], 1);
        } else {
            mybk[k] = -1;
        }
    }
    __syncthreads();
    for (int b = tid; b < NBUCK; b += 256) {
        gbase[b] = hist[b] ? atomicAdd(&gcur[b], hist[b]) : 0;
        hist[b] = 0;
    }
    __syncthreads();
#pragma unroll
    for (int k = 0; k < 16; ++k) {
        if (mybk[k] >= 0) {
            int b = mybk[k];
            int slot = gbase[b] + atomicAdd(&hist[b], 1);
            ebuf[slot] = pk[k];
        }
    }
}

// ---- GEMM body: h1h(bf16, [2][N][64] half-planes) = x @ W1, one 64-row tile ----
__device__ __forceinline__ void gemm_body(char* smem, int tile,
                                          const float* __restrict__ x,
                                          const float* __restrict__ W1,
                                          unsigned short* __restrict__ h1h) {
    if (tile >= GTILES) return;
    unsigned short* Wt = (unsigned short*)smem;           // 32 KB
    int tid = threadIdx.x;
    for (int idx = tid; idx < DIM * DIM; idx += 256) {
        int k = idx >> 7, c = idx & 127;
        Wt[c * 128 + (k ^ ((c & 7) << 3))] = f2bf(W1[idx]);
    }
    __syncthreads();

    int wv = tid >> 6, lane = tid & 63;
    int g = lane >> 4, tl = lane & 15;
    unsigned short* cst = (unsigned short*)(smem + 32768 + wv * 4096);

    int rb = tile * 64 + wv * 16;
    if (rb >= N_NODES) return;

    s16x8 afrag[4];
    const float* xrow = x + (size_t)(rb + tl) * DIM + g * 8;
#pragma unroll
    for (int kc = 0; kc < 4; ++kc) {
        float4 p0 = *(const float4*)(xrow + kc * 32);
        float4 p1 = *(const float4*)(xrow + kc * 32 + 4);
        s16x8 a;
        a[0] = (short)f2bf(p0.x); a[1] = (short)f2bf(p0.y);
        a[2] = (short)f2bf(p0.z); a[3] = (short)f2bf(p0.w);
        a[4] = (short)f2bf(p1.x); a[5] = (short)f2bf(p1.y);
        a[6] = (short)f2bf(p1.z); a[7] = (short)f2bf(p1.w);
        afrag[kc] = a;
    }

    f32x4 acc[8];
#pragma unroll
    for (int ct = 0; ct < 8; ++ct) acc[ct] = (f32x4)0.0f;
#pragma unroll
    for (int kc = 0; kc < 4; ++kc) {
#pragma unroll
        for (int ct = 0; ct < 8; ++ct) {
            int crow = ct * 16 + tl;
            int boff = crow * 256 + ((kc * 64 + g * 16) ^ ((crow & 7) << 4));
            s16x8 b = *(const s16x8*)((const char*)Wt + boff);
            acc[ct] = __builtin_amdgcn_mfma_f32_16x16x32_bf16(afrag[kc], b, acc[ct], 0, 0, 0);
        }
    }

#pragma unroll
    for (int ct = 0; ct < 8; ++ct) {
#pragma unroll
        for (int r = 0; r < 4; ++r) {
            float own = acc[ct][r];
            float oth = __shfl_xor(own, 1, 64);
            if ((lane & 1) == 0) {
                unsigned pk = (unsigned)f2bf(own) | ((unsigned)f2bf(oth) << 16);
                int row = g * 4 + r;
                int col = ct * 16 + tl;
                *(unsigned*)&cst[row * 128 + (col ^ (row << 3))] = pk;
            }
        }
    }
    asm volatile("s_waitcnt lgkmcnt(0)" ::: "memory");

    int hf = tl >> 3, ch = (tl & 7) * 8;   // half-plane / col-within-half
#pragma unroll
    for (int c = 0; c < 4; ++c) {
        int row = c * 4 + g;
        uint4 v = *(const uint4*)&cst[row * 128 + ((tl ^ row) * 8)];
        *(uint4*)(h1h + (size_t)hf * HALF_ELEMS + (size_t)(rb + row) * 64 + ch) = v;
    }
}

// standalone kernels (fallback path when ws is tight)
__global__ __launch_bounds__(256) void k_part(const int* __restrict__ src,
                                              const int* __restrict__ dst,
                                              int* __restrict__ gcur,
                                              int* __restrict__ ebuf) {
    __shared__ __align__(16) char smem[2 * NBUCK * 4 + 16];
    part_body(smem, blockIdx.x, src, dst, gcur, ebuf);
}

__global__ __launch_bounds__(256) void k_gemm(const float* __restrict__ x,
                                              const float* __restrict__ W1,
                                              unsigned short* __restrict__ h1h) {
    __shared__ __align__(16) char smem[49152];
    gemm_body(smem, blockIdx.x, x, W1, h1h);
}

// merged CSR: count, scan, emit src-only lists (one bucket per block)
__global__ __launch_bounds__(256) void k_csrk(const int* __restrict__ ebuf,
                                              const int* __restrict__ gcur,
                                              int* __restrict__ rp,
                                              int* __restrict__ cnt,
                                              float* __restrict__ dinv,
                                              int* __restrict__ csrs) {
    __shared__ int lcnt[BNODES];
    __shared__ int lcur[BNODES];
    int b = blockIdx.x, t = threadIdx.x;
    int node0 = b << BSHIFT;
    lcnt[t] = 0;
    __syncthreads();
    int base = b * BCAP, end = gcur[b];
    for (int e = base + t; e < end; e += 256)
        atomicAdd(&lcnt[ebuf[e] & 255], 1);
    __syncthreads();
    int c = lcnt[t];
    lcur[t] = c;
    __syncthreads();
    for (int s = 1; s < 256; s <<= 1) {
        int u = (t >= s) ? lcur[t - s] : 0;
        __syncthreads();
        lcur[t] += u;
        __syncthreads();
    }
    int excl = lcur[t] - c;
    lcur[t] = excl;           // becomes emit cursor
    int node = node0 + t;
    if (node < N_NODES) {
        rp[node] = base + excl;
        cnt[node] = c;
        dinv[node] = rsqrtf((float)(c + 1));
    }
    __syncthreads();
    for (int e = base + t; e < end; e += 256) {
        int pkd = ebuf[e];
        int p = atomicAdd(&lcur[pkd & 255], 1);
        csrs[base + p] = (int)((unsigned)pkd >> 8);
    }
}

// fused: part(391 blocks) || gemm(1563 blocks x 1 tile) — R12's best interleave
__global__ __launch_bounds__(256) void k_pg(const int* __restrict__ src,
                                            const int* __restrict__ dst,
                                            int* __restrict__ gcur,
                                            int* __restrict__ ebuf,
                                            const float* __restrict__ x,
                                            const float* __restrict__ W1,
                                            unsigned short* __restrict__ h1h) {
    __shared__ __align__(16) char smem[49152];
    if (blockIdx.x < NB_PART) part_body(smem, blockIdx.x, src, dst, gcur, ebuf);
    else                      gemm_body(smem, blockIdx.x - NB_PART, x, W1, h1h);
}

// ---------------- agg1 halved (R13 winner): half = blockIdx&1 ----------------

__global__ __launch_bounds__(256) void k_agg1h(const unsigned short* __restrict__ h1h,
                                               const float* __restrict__ dinv,
                                               const int* __restrict__ rp,
                                               const int* __restrict__ cnt,
                                               const int* __restrict__ csrs,
                                               const float* __restrict__ b1,
                                               const float* __restrict__ W2,
                                               float* __restrict__ zpart) {
    int half = blockIdx.x & 1;
    int nb = blockIdx.x >> 1;            // 0..3124
    int lane = threadIdx.x & 63;
    int wv = threadIdx.x >> 6;
    int g = lane >> 3, tl = lane & 7;
    int i = nb * 32 + wv * 8 + g;
    int c0 = tl * 8;                     // col within half
    const unsigned short* hbase = h1h + (size_t)half * HALF_ELEMS + c0;
    float di = dinv[i];
    int beg = rp[i], end = beg + cnt[i];
    float a[8];
#pragma unroll
    for (int q = 0; q < 8; ++q) a[q] = 0.f;

    int j = beg;
    for (; j + 4 <= end; j += 4) {
        int s0 = csrs[j], s1 = csrs[j + 1], s2 = csrs[j + 2], s3 = csrs[j + 3];
        uint4 v0 = *(const uint4*)(hbase + (size_t)s0 * 64);
        uint4 v1 = *(const uint4*)(hbase + (size_t)s1 * 64);
        uint4 v2 = *(const uint4*)(hbase + (size_t)s2 * 64);
        uint4 v3 = *(const uint4*)(hbase + (size_t)s3 * 64);
        float w0 = dinv[s0] * di, w1 = dinv[s1] * di;
        float w2 = dinv[s2] * di, w3 = dinv[s3] * di;
        acc8(a, v0, w0);
        acc8(a, v1, w1);
        acc8(a, v2, w2);
        acc8(a, v3, w3);
    }
    for (; j < end; ++j) {
        int s0 = csrs[j];
        uint4 v0 = *(const uint4*)(hbase + (size_t)s0 * 64);
        acc8(a, v0, dinv[s0] * di);
    }

    uint4 vs = *(const uint4*)(hbase + (size_t)i * 64);
    float sii = di * di;
    int cb = half * 64 + c0;
    float4 bA = *(const float4*)(b1 + cb);
    float4 bB = *(const float4*)(b1 + cb + 4);
    float4 wA = *(const float4*)(W2 + cb);
    float4 wB = *(const float4*)(W2 + cb + 4);
    float p = 0.f;
    p += fmaxf(fmaf(bflo(vs.x), sii, a[0]) + bA.x, 0.f) * wA.x;
    p += fmaxf(fmaf(bfhi(vs.x), sii, a[1]) + bA.y, 0.f) * wA.y;
    p += fmaxf(fmaf(bflo(vs.y), sii, a[2]) + bA.z, 0.f) * wA.z;
    p += fmaxf(fmaf(bfhi(vs.y), sii, a[3]) + bA.w, 0.f) * wA.w;
    p += fmaxf(fmaf(bflo(vs.z), sii, a[4]) + bB.x, 0.f) * wB.x;
    p += fmaxf(fmaf(bfhi(vs.z), sii, a[5]) + bB.y, 0.f) * wB.y;
    p += fmaxf(fmaf(bflo(vs.w), sii, a[6]) + bB.z, 0.f) * wB.z;
    p += fmaxf(fmaf(bfhi(vs.w), sii, a[7]) + bB.w, 0.f) * wB.w;
#pragma unroll
    for (int off = 4; off >= 1; off >>= 1) p += __shfl_xor(p, off, 64);
    if (tl == 0) zpart[(size_t)half * N_NODES + i] = p;
}

// ---------------- agg2: 4 lanes/node, zred folded in (z = zp0 + zp1) ----------------

__global__ __launch_bounds__(256) void k_agg2(const float* __restrict__ zpart,
                                              const float* __restrict__ dinv,
                                              const int* __restrict__ rp,
                                              const int* __restrict__ cnt,
                                              const int* __restrict__ csrs,
                                              const float* __restrict__ b2,
                                              float* __restrict__ out) {
    int grp = threadIdx.x >> 2, r = threadIdx.x & 3;
    int i = blockIdx.x * 64 + grp;
    if (i >= N_NODES) return;
    float di = dinv[i];
    int beg = rp[i], end = beg + cnt[i];
    float acc = 0.f;
    for (int j = beg + r; j < end; j += 4) {
        int s = csrs[j];
        float zs = zpart[s] + zpart[N_NODES + s];
        acc = fmaf(zs, dinv[s] * di, acc);
    }
    acc += __shfl_xor(acc, 1, 64);
    acc += __shfl_xor(acc, 2, 64);
    if (r == 0) {
        float zi = zpart[i] + zpart[N_NODES + i];
        out[i] = acc + zi * di * di + b2[0];
    }
}

// ---------------- launch ----------------

extern "C" void kernel_launch(void* const* d_in, const int* in_sizes, int n_in,
                              void* d_out, int out_size, void* d_ws, size_t ws_size,
                              hipStream_t stream) {
    const float* x  = (const float*)d_in[0];
    const int*   ei = (const int*)d_in[1];
    const float* W1 = (const float*)d_in[2];
    const float* b1 = (const float*)d_in[3];
    const float* W2 = (const float*)d_in[4];
    const float* b2 = (const float*)d_in[5];
    float* out = (float*)d_out;

    const int* src = ei;
    const int* dst = ei + N_EDGES;

    char* ws = (char*)d_ws;
    size_t o = 0;
    auto take = [&](size_t bytes) { char* p = ws + o; o += (bytes + 255) & ~(size_t)255; return p; };
    int*   cnt   = (int*)take(sizeof(int) * N_NODES);
    int*   rp    = (int*)take(sizeof(int) * N_NODES);
    int*   gcur  = (int*)take(sizeof(int) * (NBUCK + 1));
    float* dinv  = (float*)take(sizeof(float) * N_NODES);
    float* zpart = (float*)take(sizeof(float) * 2 * N_NODES);
    int*   csrs  = (int*)take(sizeof(int) * (size_t)NBUCK * BCAP);
    unsigned short* h1h = (unsigned short*)take(sizeof(unsigned short) * 2 * HALF_ELEMS);
    int* ebuf_sep = (int*)take(sizeof(int) * (size_t)NBUCK * BCAP);
    bool fused = (o <= ws_size);
    int* ebuf = fused ? ebuf_sep : (int*)h1h;  // fallback alias: ebuf dead before gemm writes h1h

    k_zero<<<2, 256, 0, stream>>>(gcur);
    if (fused) {
        k_pg<<<NB_PART + GTILES, 256, 0, stream>>>(src, dst, gcur, ebuf, x, W1, h1h);
        k_csrk<<<NBUCK, 256, 0, stream>>>(ebuf, gcur, rp, cnt, dinv, csrs);
    } else {
        k_part<<<NB_PART, 256, 0, stream>>>(src, dst, gcur, ebuf);
        k_csrk<<<NBUCK, 256, 0, stream>>>(ebuf, gcur, rp, cnt, dinv, csrs);
        k_gemm<<<GTILES, 256, 0, stream>>>(x, W1, h1h);  // after last ebuf read
    }
    k_agg1h<<<2 * (N_NODES / 32), 256, 0, stream>>>(h1h, dinv, rp, cnt, csrs, b1, W2, zpart);
    k_agg2<<<(N_NODES + 63) / 64, 256, 0, stream>>>(zpart, dinv, rp, cnt, csrs, b2, out);
}

// Round 19
// 143.573 us; speedup vs baseline: 1.1418x; 1.0042x over previous
//
#include <hip/hip_runtime.h>

#define N_NODES 100000
#define N_EDGES 1600000
#define DIM 128

#define BSHIFT 8
#define BNODES 256
#define NBUCK 391     // ceil(100000/256)
#define BCAP  4608    // padded bucket capacity
#define PCHUNK 4096
#define NB_PART ((N_EDGES + PCHUNK - 1) / PCHUNK)  // 391

#define GTILES 1563   // ceil(100000/64)
#define GHALF  625    // gemm tiles co-dispatched with part (rest go with csr)

#define HALF_ELEMS ((size_t)N_NODES * 64)   // one 64-col half-plane of h1

typedef short s16x8 __attribute__((ext_vector_type(8)));
typedef float f32x4 __attribute__((ext_vector_type(4)));

__device__ __forceinline__ unsigned short f2bf(float f) {
    unsigned u = __float_as_uint(f);
    u += 0x7fffu + ((u >> 16) & 1u);   // RNE
    return (unsigned short)(u >> 16);
}
__device__ __forceinline__ float bflo(unsigned u) { return __uint_as_float(u << 16); }
__device__ __forceinline__ float bfhi(unsigned u) { return __uint_as_float(u & 0xffff0000u); }

__device__ __forceinline__ void acc8(float (&a)[8], uint4 v, float w) {
    a[0] = fmaf(bflo(v.x), w, a[0]); a[1] = fmaf(bfhi(v.x), w, a[1]);
    a[2] = fmaf(bflo(v.y), w, a[2]); a[3] = fmaf(bfhi(v.y), w, a[3]);
    a[4] = fmaf(bflo(v.z), w, a[4]); a[5] = fmaf(bfhi(v.z), w, a[5]);
    a[6] = fmaf(bflo(v.w), w, a[6]); a[7] = fmaf(bfhi(v.w), w, a[7]);
}

// ---------------- CSR build (padded buckets, packed 4B ebuf entries) ----------------
// entry = (src << 8) | (dst & 255); bucket = dst >> 8 (implicit in position)

__global__ void k_zero(int* __restrict__ gcur) {
    int t = blockIdx.x * blockDim.x + threadIdx.x;
    if (t < NBUCK) gcur[t] = t * BCAP;
}

__device__ __forceinline__ void part_body(char* smem, int bid,
                                          const int* __restrict__ src,
                                          const int* __restrict__ dst,
                                          int* __restrict__ gcur,
                                          int* __restrict__ ebuf) {
    int* hist = (int*)smem;
    int* gbase = hist + NBUCK;
    int tid = threadIdx.x;
    long e0 = (long)bid * PCHUNK;
    int n = min(PCHUNK, (int)(N_EDGES - e0));
    for (int b = tid; b < NBUCK; b += 256) hist[b] = 0;
    __syncthreads();

    int pk[16], mybk[16];
#pragma unroll
    for (int k = 0; k < 16; ++k) {
        int idx = k * 256 + tid;
        if (idx < n) {
            int s = src[e0 + idx], d = dst[e0 + idx];
            mybk[k] = d >> BSHIFT;
            pk[k] = (s << 8) | (d & 255);
            atomicAdd(&hist[mybk[k]], 1);
        } else {
            mybk[k] = -1;
        }
    }
    __syncthreads();
    for (int b = tid; b < NBUCK; b += 256) {
        gbase[b] = hist[b] ? atomicAdd(&gcur[b], hist[b]) : 0;
        hist[b] = 0;
    }
    __syncthreads();
#pragma unroll
    for (int k = 0; k < 16; ++k) {
        if (mybk[k] >= 0) {
            int b = mybk[k];
            int slot = gbase[b] + atomicAdd(&hist[b], 1);
            ebuf[slot] = pk[k];
        }
    }
}

// merged CSR body: count, scan, emit src-only lists (one bucket per block)
__device__ __forceinline__ void csr_body(char* smem, int b,
                                         const int* __restrict__ ebuf,
                                         const int* __restrict__ gcur,
                                         int* __restrict__ rp,
                                         int* __restrict__ cnt,
                                         float* __restrict__ dinv,
                                         int* __restrict__ csrs) {
    int* lcnt = (int*)smem;
    int* lcur = lcnt + BNODES;
    int t = threadIdx.x;
    int node0 = b << BSHIFT;
    lcnt[t] = 0;
    __syncthreads();
    int base = b * BCAP, end = gcur[b];
    for (int e = base + t; e < end; e += 256)
        atomicAdd(&lcnt[ebuf[e] & 255], 1);
    __syncthreads();
    int c = lcnt[t];
    lcur[t] = c;
    __syncthreads();
    for (int s = 1; s < 256; s <<= 1) {
        int u = (t >= s) ? lcur[t - s] : 0;
        __syncthreads();
        lcur[t] += u;
        __syncthreads();
    }
    int excl = lcur[t] - c;
    lcur[t] = excl;           // becomes emit cursor
    int node = node0 + t;
    if (node < N_NODES) {
        rp[node] = base + excl;
        cnt[node] = c;
        dinv[node] = rsqrtf((float)(c + 1));
    }
    __syncthreads();
    for (int e = base + t; e < end; e += 256) {
        int pkd = ebuf[e];
        int p = atomicAdd(&lcur[pkd & 255], 1);
        csrs[base + p] = (int)((unsigned)pkd >> 8);
    }
}

// ---- GEMM body: h1h(bf16, [2][N][64] half-planes) = x @ W1, one 64-row tile ----
__device__ __forceinline__ void gemm_body(char* smem, int tile,
                                          const float* __restrict__ x,
                                          const float* __restrict__ W1,
                                          unsigned short* __restrict__ h1h) {
    if (tile >= GTILES) return;
    unsigned short* Wt = (unsigned short*)smem;           // 32 KB
    int tid = threadIdx.x;
    for (int idx = tid; idx < DIM * DIM; idx += 256) {
        int k = idx >> 7, c = idx & 127;
        Wt[c * 128 + (k ^ ((c & 7) << 3))] = f2bf(W1[idx]);
    }
    __syncthreads();

    int wv = tid >> 6, lane = tid & 63;
    int g = lane >> 4, tl = lane & 15;
    unsigned short* cst = (unsigned short*)(smem + 32768 + wv * 4096);

    int rb = tile * 64 + wv * 16;
    if (rb >= N_NODES) return;

    s16x8 afrag[4];
    const float* xrow = x + (size_t)(rb + tl) * DIM + g * 8;
#pragma unroll
    for (int kc = 0; kc < 4; ++kc) {
        float4 p0 = *(const float4*)(xrow + kc * 32);
        float4 p1 = *(const float4*)(xrow + kc * 32 + 4);
        s16x8 a;
        a[0] = (short)f2bf(p0.x); a[1] = (short)f2bf(p0.y);
        a[2] = (short)f2bf(p0.z); a[3] = (short)f2bf(p0.w);
        a[4] = (short)f2bf(p1.x); a[5] = (short)f2bf(p1.y);
        a[6] = (short)f2bf(p1.z); a[7] = (short)f2bf(p1.w);
        afrag[kc] = a;
    }

    f32x4 acc[8];
#pragma unroll
    for (int ct = 0; ct < 8; ++ct) acc[ct] = (f32x4)0.0f;
#pragma unroll
    for (int kc = 0; kc < 4; ++kc) {
#pragma unroll
        for (int ct = 0; ct < 8; ++ct) {
            int crow = ct * 16 + tl;
            int boff = crow * 256 + ((kc * 64 + g * 16) ^ ((crow & 7) << 4));
            s16x8 b = *(const s16x8*)((const char*)Wt + boff);
            acc[ct] = __builtin_amdgcn_mfma_f32_16x16x32_bf16(afrag[kc], b, acc[ct], 0, 0, 0);
        }
    }

#pragma unroll
    for (int ct = 0; ct < 8; ++ct) {
#pragma unroll
        for (int r = 0; r < 4; ++r) {
            float own = acc[ct][r];
            float oth = __shfl_xor(own, 1, 64);
            if ((lane & 1) == 0) {
                unsigned pk = (unsigned)f2bf(own) | ((unsigned)f2bf(oth) << 16);
                int row = g * 4 + r;
                int col = ct * 16 + tl;
                *(unsigned*)&cst[row * 128 + (col ^ (row << 3))] = pk;
            }
        }
    }
    asm volatile("s_waitcnt lgkmcnt(0)" ::: "memory");

    int hf = tl >> 3, ch = (tl & 7) * 8;   // half-plane / col-within-half
#pragma unroll
    for (int c = 0; c < 4; ++c) {
        int row = c * 4 + g;
        uint4 v = *(const uint4*)&cst[row * 128 + ((tl ^ row) * 8)];
        *(uint4*)(h1h + (size_t)hf * HALF_ELEMS + (size_t)(rb + row) * 64 + ch) = v;
    }
}

// standalone kernels (fallback path when ws is tight)
__global__ __launch_bounds__(256) void k_part(const int* __restrict__ src,
                                              const int* __restrict__ dst,
                                              int* __restrict__ gcur,
                                              int* __restrict__ ebuf) {
    __shared__ __align__(16) char smem[2 * NBUCK * 4 + 16];
    part_body(smem, blockIdx.x, src, dst, gcur, ebuf);
}

__global__ __launch_bounds__(256) void k_gemm(const float* __restrict__ x,
                                              const float* __restrict__ W1,
                                              unsigned short* __restrict__ h1h) {
    __shared__ __align__(16) char smem[49152];
    gemm_body(smem, blockIdx.x, x, W1, h1h);
}

__global__ __launch_bounds__(256) void k_csrk(const int* __restrict__ ebuf,
                                              const int* __restrict__ gcur,
                                              int* __restrict__ rp,
                                              int* __restrict__ cnt,
                                              float* __restrict__ dinv,
                                              int* __restrict__ csrs) {
    __shared__ __align__(16) char smem[2 * BNODES * 4];
    csr_body(smem, blockIdx.x, ebuf, gcur, rp, cnt, dinv, csrs);
}

// fused D1: part || gemm tiles [0, GHALF)
__global__ __launch_bounds__(256) void k_pg1(const int* __restrict__ src,
                                             const int* __restrict__ dst,
                                             int* __restrict__ gcur,
                                             int* __restrict__ ebuf,
                                             const float* __restrict__ x,
                                             const float* __restrict__ W1,
                                             unsigned short* __restrict__ h1h) {
    __shared__ __align__(16) char smem[49152];
    if (blockIdx.x < NB_PART) part_body(smem, blockIdx.x, src, dst, gcur, ebuf);
    else                      gemm_body(smem, blockIdx.x - NB_PART, x, W1, h1h);
}

// fused D2: csr || gemm tiles [GHALF, GTILES)
__global__ __launch_bounds__(256) void k_pg2(const int* __restrict__ ebuf,
                                             const int* __restrict__ gcur,
                                             int* __restrict__ rp,
                                             int* __restrict__ cnt,
                                             float* __restrict__ dinv,
                                             int* __restrict__ csrs,
                                             const float* __restrict__ x,
                                             const float* __restrict__ W1,
                                             unsigned short* __restrict__ h1h) {
    __shared__ __align__(16) char smem[49152];
    if (blockIdx.x < NBUCK) csr_body(smem, blockIdx.x, ebuf, gcur, rp, cnt, dinv, csrs);
    else                    gemm_body(smem, GHALF + (blockIdx.x - NBUCK), x, W1, h1h);
}

// ---------------- agg1 halved (R13 winner): half = blockIdx&1 ----------------

__global__ __launch_bounds__(256) void k_agg1h(const unsigned short* __restrict__ h1h,
                                               const float* __restrict__ dinv,
                                               const int* __restrict__ rp,
                                               const int* __restrict__ cnt,
                                               const int* __restrict__ csrs,
                                               const float* __restrict__ b1,
                                               const float* __restrict__ W2,
                                               float* __restrict__ zpart) {
    int half = blockIdx.x & 1;
    int nb = blockIdx.x >> 1;            // 0..3124
    int lane = threadIdx.x & 63;
    int wv = threadIdx.x >> 6;
    int g = lane >> 3, tl = lane & 7;
    int i = nb * 32 + wv * 8 + g;
    int c0 = tl * 8;                     // col within half
    const unsigned short* hbase = h1h + (size_t)half * HALF_ELEMS + c0;
    float di = dinv[i];
    int beg = rp[i], end = beg + cnt[i];
    float a[8];
#pragma unroll
    for (int q = 0; q < 8; ++q) a[q] = 0.f;

    int j = beg;
    for (; j + 4 <= end; j += 4) {
        int s0 = csrs[j], s1 = csrs[j + 1], s2 = csrs[j + 2], s3 = csrs[j + 3];
        uint4 v0 = *(const uint4*)(hbase + (size_t)s0 * 64);
        uint4 v1 = *(const uint4*)(hbase + (size_t)s1 * 64);
        uint4 v2 = *(const uint4*)(hbase + (size_t)s2 * 64);
        uint4 v3 = *(const uint4*)(hbase + (size_t)s3 * 64);
        float w0 = dinv[s0] * di, w1 = dinv[s1] * di;
        float w2 = dinv[s2] * di, w3 = dinv[s3] * di;
        acc8(a, v0, w0);
        acc8(a, v1, w1);
        acc8(a, v2, w2);
        acc8(a, v3, w3);
    }
    for (; j < end; ++j) {
        int s0 = csrs[j];
        uint4 v0 = *(const uint4*)(hbase + (size_t)s0 * 64);
        acc8(a, v0, dinv[s0] * di);
    }

    uint4 vs = *(const uint4*)(hbase + (size_t)i * 64);
    float sii = di * di;
    int cb = half * 64 + c0;
    float4 bA = *(const float4*)(b1 + cb);
    float4 bB = *(const float4*)(b1 + cb + 4);
    float4 wA = *(const float4*)(W2 + cb);
    float4 wB = *(const float4*)(W2 + cb + 4);
    float p = 0.f;
    p += fmaxf(fmaf(bflo(vs.x), sii, a[0]) + bA.x, 0.f) * wA.x;
    p += fmaxf(fmaf(bfhi(vs.x), sii, a[1]) + bA.y, 0.f) * wA.y;
    p += fmaxf(fmaf(bflo(vs.y), sii, a[2]) + bA.z, 0.f) * wA.z;
    p += fmaxf(fmaf(bfhi(vs.y), sii, a[3]) + bA.w, 0.f) * wA.w;
    p += fmaxf(fmaf(bflo(vs.z), sii, a[4]) + bB.x, 0.f) * wB.x;
    p += fmaxf(fmaf(bfhi(vs.z), sii, a[5]) + bB.y, 0.f) * wB.y;
    p += fmaxf(fmaf(bflo(vs.w), sii, a[6]) + bB.z, 0.f) * wB.z;
    p += fmaxf(fmaf(bfhi(vs.w), sii, a[7]) + bB.w, 0.f) * wB.w;
#pragma unroll
    for (int off = 4; off >= 1; off >>= 1) p += __shfl_xor(p, off, 64);
    if (tl == 0) zpart[(size_t)half * N_NODES + i] = p;
}

// ---------------- agg2: 4 lanes/node, zred folded in (z = zp0 + zp1) ----------------

__global__ __launch_bounds__(256) void k_agg2(const float* __restrict__ zpart,
                                              const float* __restrict__ dinv,
                                              const int* __restrict__ rp,
                                              const int* __restrict__ cnt,
                                              const int* __restrict__ csrs,
                                              const float* __restrict__ b2,
                                              float* __restrict__ out) {
    int grp = threadIdx.x >> 2, r = threadIdx.x & 3;
    int i = blockIdx.x * 64 + grp;
    if (i >= N_NODES) return;
    float di = dinv[i];
    int beg = rp[i], end = beg + cnt[i];
    float acc = 0.f;
    for (int j = beg + r; j < end; j += 4) {
        int s = csrs[j];
        float zs = zpart[s] + zpart[N_NODES + s];
        acc = fmaf(zs, dinv[s] * di, acc);
    }
    acc += __shfl_xor(acc, 1, 64);
    acc += __shfl_xor(acc, 2, 64);
    if (r == 0) {
        float zi = zpart[i] + zpart[N_NODES + i];
        out[i] = acc + zi * di * di + b2[0];
    }
}

// ---------------- launch ----------------

extern "C" void kernel_launch(void* const* d_in, const int* in_sizes, int n_in,
                              void* d_out, int out_size, void* d_ws, size_t ws_size,
                              hipStream_t stream) {
    const float* x  = (const float*)d_in[0];
    const int*   ei = (const int*)d_in[1];
    const float* W1 = (const float*)d_in[2];
    const float* b1 = (const float*)d_in[3];
    const float* W2 = (const float*)d_in[4];
    const float* b2 = (const float*)d_in[5];
    float* out = (float*)d_out;

    const int* src = ei;
    const int* dst = ei + N_EDGES;

    char* ws = (char*)d_ws;
    size_t o = 0;
    auto take = [&](size_t bytes) { char* p = ws + o; o += (bytes + 255) & ~(size_t)255; return p; };
    int*   cnt   = (int*)take(sizeof(int) * N_NODES);
    int*   rp    = (int*)take(sizeof(int) * N_NODES);
    int*   gcur  = (int*)take(sizeof(int) * (NBUCK + 1));
    float* dinv  = (float*)take(sizeof(float) * N_NODES);
    float* zpart = (float*)take(sizeof(float) * 2 * N_NODES);
    int*   csrs  = (int*)take(sizeof(int) * (size_t)NBUCK * BCAP);
    unsigned short* h1h = (unsigned short*)take(sizeof(unsigned short) * 2 * HALF_ELEMS);
    int* ebuf_sep = (int*)take(sizeof(int) * (size_t)NBUCK * BCAP);
    bool fused = (o <= ws_size);
    int* ebuf = fused ? ebuf_sep : (int*)h1h;  // fallback alias: ebuf dead before gemm writes h1h

    k_zero<<<2, 256, 0, stream>>>(gcur);
    if (fused) {
        k_pg1<<<NB_PART + GHALF, 256, 0, stream>>>(src, dst, gcur, ebuf, x, W1, h1h);
        k_pg2<<<NBUCK + (GTILES - GHALF), 256, 0, stream>>>(ebuf, gcur, rp, cnt, dinv, csrs, x, W1, h1h);
    } else {
        k_part<<<NB_PART, 256, 0, stream>>>(src, dst, gcur, ebuf);
        k_csrk<<<NBUCK, 256, 0, stream>>>(ebuf, gcur, rp, cnt, dinv, csrs);
        k_gemm<<<GTILES, 256, 0, stream>>>(x, W1, h1h);  // after last ebuf read
    }
    k_agg1h<<<2 * (N_NODES / 32), 256, 0, stream>>>(h1h, dinv, rp, cnt, csrs, b1, W2, zpart);
    k_agg2<<<(N_NODES + 63) / 64, 256, 0, stream>>>(zpart, dinv, rp, cnt, csrs, b2, out);
}